// Round 5
// baseline (341.891 us; speedup 1.0000x reference)
//
#include <hip/hip_runtime.h>
#include <hip/hip_bf16.h>

#define B_SZ   2
#define C_CH   64
#define NQ     8          // q/k channels (C/8)
#define NPIX   9216       // 96*96
#define QTILES 576        // NPIX/16
#define KPART  4          // key partitions, one per wave in a block
#define KEYS_P 2304       // NPIX/KPART
#define NCHUNK 36         // KEYS_P/64
#define PART_F 1056       // per-partition LDS floats: 16*64 O + 16 m + 16 l
#define PT_W   36         // u32 per P-row (32 used + 4 pad: 144B row = b128-aligned)

typedef short bf16x8 __attribute__((ext_vector_type(8)));
typedef float f32x4  __attribute__((ext_vector_type(4)));

static __device__ __forceinline__ unsigned pack2bf(float a, float b){
    union { __hip_bfloat16 h; unsigned short us; } ca, cb;
    ca.h = __float2bfloat16(a); cb.h = __float2bfloat16(b);
    return (unsigned)ca.us | ((unsigned)cb.us << 16);
}

// ---------- projections (fp32 in): q,k -> [b][n][8] bf16 ; v -> [b][c][n] bf16 ----------
__global__ void proj_qk(const float* __restrict__ x,
                        const float* __restrict__ wq, const float* __restrict__ bq,
                        const float* __restrict__ wk, const float* __restrict__ bk,
                        __hip_bfloat16* __restrict__ qp, __hip_bfloat16* __restrict__ kp)
{
    int t = blockIdx.x * blockDim.x + threadIdx.x;   // (b,n)
    int b = t / NPIX, n = t - b * NPIX;
    float qa[NQ], ka[NQ];
#pragma unroll
    for (int o = 0; o < NQ; ++o){ qa[o] = bq[o]; ka[o] = bk[o]; }
    for (int c = 0; c < C_CH; ++c){
        float xv = x[(size_t)(b*C_CH + c)*NPIX + n];        // coalesced over n
#pragma unroll
        for (int o = 0; o < NQ; ++o){
            qa[o] = fmaf(xv, wq[o*C_CH + c], qa[o]);        // wave-uniform weight loads
            ka[o] = fmaf(xv, wk[o*C_CH + c], ka[o]);
        }
    }
#pragma unroll
    for (int o = 0; o < NQ; ++o){
        qp[(size_t)t*NQ + o] = __float2bfloat16(qa[o]);
        kp[(size_t)t*NQ + o] = __float2bfloat16(ka[o]);
    }
}

__global__ void proj_v(const float* __restrict__ x,
                       const float* __restrict__ wv, const float* __restrict__ bv,
                       __hip_bfloat16* __restrict__ vp)
{
    int t  = blockIdx.x * blockDim.x + threadIdx.x;  // (b, cg, n): cg = group of 16 out-channels
    int n  = t % NPIX;
    int bc = t / NPIX;
    int b  = bc >> 2, cg = bc & 3;
    float acc[16];
#pragma unroll
    for (int o = 0; o < 16; ++o) acc[o] = bv[cg*16 + o];
    for (int ci = 0; ci < C_CH; ++ci){
        float xv = x[(size_t)(b*C_CH + ci)*NPIX + n];
#pragma unroll
        for (int o = 0; o < 16; ++o)
            acc[o] = fmaf(xv, wv[(cg*16 + o)*C_CH + ci], acc[o]);
    }
#pragma unroll
    for (int o = 0; o < 16; ++o)
        vp[(size_t)(b*C_CH + cg*16 + o)*NPIX + n] = __float2bfloat16(acc[o]);
}

// ---------- SE branch: GAP + 2x (linear+BN+relu) ----------
__global__ void gap_kernel(const float* __restrict__ x, float* __restrict__ amean)
{
    int bc = blockIdx.x;                 // (b*64+c)
    int tid = threadIdx.x;
    float s = 0.f;
    for (int i = tid; i < NPIX; i += 256) s += x[(size_t)bc*NPIX + i];
#pragma unroll
    for (int o = 32; o > 0; o >>= 1) s += __shfl_down(s, o, 64);
    __shared__ float red[4];
    if ((tid & 63) == 0) red[tid >> 6] = s;
    __syncthreads();
    if (tid == 0) amean[bc] = (red[0] + red[1] + red[2] + red[3]) * (1.f / (float)NPIX);
}

__global__ void se_kernel(const float* __restrict__ amean,
                          const float* w1, const float* b1,
                          const float* n1w, const float* n1b,
                          const float* n1m, const float* n1v,
                          const float* w2, const float* b2,
                          const float* n2w, const float* n2b,
                          const float* n2m, const float* n2v,
                          float* __restrict__ a2)
{
    __shared__ float a1s[B_SZ][NQ];
    int t = threadIdx.x;
    if (t < B_SZ * NQ){
        int b = t >> 3, r = t & 7;
        float s = b1[r];
        for (int c = 0; c < C_CH; ++c) s = fmaf(amean[b*C_CH + c], w1[r*C_CH + c], s);
        s = (s - n1m[r]) * (n1w[r] * rsqrtf(n1v[r] + 1e-5f)) + n1b[r];
        a1s[b][r] = fmaxf(s, 0.f);
    }
    __syncthreads();
    {
        int b = t >> 6, c = t & 63;
        float s = b2[c];
#pragma unroll
        for (int r = 0; r < NQ; ++r) s = fmaf(a1s[b][r], w2[c*NQ + r], s);
        s = (s - n2m[c]) * (n2w[c] * rsqrtf(n2v[c] + 1e-5f)) + n2b[c];
        a2[b*C_CH + c] = fmaxf(s, 0.f);
    }
}

// ---------- fused flash attention + combine + epilogue ----------
// Block = 4 waves; wave p handles key-partition p (flash-decoding split).
// S^T = K·Q^T via mfma (m=key, n=query, K-dim = 8 padded to 32: only lane-group 0 real).
// Softmax state per lane scalar (query = lane&15, replicated over lane>>4 groups).
// P^T C-layout -> B-operand layout via per-wave LDS round-trip (m120-verified pattern).
// O^T[c][q] accumulated in 4 C-frags; partitions merged in LDS; BN/SE/residual fused.
__global__ __launch_bounds__(256) void flash_fused(
    const __hip_bfloat16* __restrict__ qp,
    const __hip_bfloat16* __restrict__ kp,
    const __hip_bfloat16* __restrict__ vp,
    const float* __restrict__ a2,
    const float* __restrict__ x,
    const float* __restrict__ gamma,
    const float* __restrict__ bnw, const float* __restrict__ bnb,
    const float* __restrict__ bnm, const float* __restrict__ bnv,
    float* __restrict__ out)
{
    __shared__ __align__(16) float    smem[KPART][PART_F];   // partition partials
    __shared__ __align__(16) unsigned ptls[KPART][16][PT_W]; // per-wave P: [query][key-pair u32]

    const int qt = blockIdx.x, b = blockIdx.y;
    const int p  = threadIdx.x >> 6;     // wave = key partition
    const int l  = threadIdx.x & 63;
    const int lq = l & 15;               // query column
    const int lg = l >> 4;               // lane group

    bf16x8 zfrag = {0,0,0,0,0,0,0,0};
    bf16x8 qfrag = zfrag;    // B-operand: B[d = lg*8+j][n = lq] = q[qt*16+lq][d]
    if (lg == 0)
        qfrag = *reinterpret_cast<const bf16x8*>(qp + (size_t)(b*NPIX + qt*16 + lq) * NQ);

    f32x4 Of[4];
#pragma unroll
    for (int i = 0; i < 4; ++i) Of[i] = (f32x4){0.f, 0.f, 0.f, 0.f};
    float m_run = -1e30f, l_run = 0.f;

    int j0 = p * KEYS_P;
    for (int ch = 0; ch < NCHUNK; ++ch, j0 += 64){
        // --- S^T = K·Q^T : Sf[jt] rows = keys j0+jt*16+4*lg+r, col = query lq ---
        f32x4 Sf[4];
#pragma unroll
        for (int jt = 0; jt < 4; ++jt){
            bf16x8 kfrag = zfrag;   // A-operand: A[m = 16jt+lq (key)][d = lg*8+j]
            if (lg == 0)
                kfrag = *reinterpret_cast<const bf16x8*>(kp + (size_t)(b*NPIX + j0 + jt*16 + lq) * NQ);
            Sf[jt] = __builtin_amdgcn_mfma_f32_16x16x32_bf16(kfrag, qfrag, (f32x4){0.f,0.f,0.f,0.f}, 0, 0, 0);
        }
        // --- online softmax: this lane holds 16 of the 64 keys for query lq ---
        float cmax = Sf[0][0];
#pragma unroll
        for (int jt = 0; jt < 4; ++jt)
#pragma unroll
            for (int r = 0; r < 4; ++r) cmax = fmaxf(cmax, Sf[jt][r]);
        cmax = fmaxf(cmax, __shfl_xor(cmax, 16, 64));
        cmax = fmaxf(cmax, __shfl_xor(cmax, 32, 64));
        float mnew  = fmaxf(m_run, cmax);
        float alpha = __expf(fminf(m_run - mnew, 0.f));   // exp arg <= 0 always
        float Pv[4][4];
        float csum = 0.f;
#pragma unroll
        for (int jt = 0; jt < 4; ++jt)
#pragma unroll
            for (int r = 0; r < 4; ++r){
                float e = __expf(fminf(Sf[jt][r] - mnew, 0.f));
                Pv[jt][r] = e; csum += e;
            }
        csum += __shfl_xor(csum, 16, 64);
        csum += __shfl_xor(csum, 32, 64);
        l_run = l_run * alpha + csum;
        m_run = mnew;
#pragma unroll
        for (int ct = 0; ct < 4; ++ct)
#pragma unroll
            for (int r = 0; r < 4; ++r) Of[ct][r] *= alpha;

        // --- P^T (C-layout) -> LDS as P[query][key] bf16, key pairs packed in u32 ---
        // Lane holds P[lq][jt*16+lg*4+r]; pairs (r=0,1),(r=2,3) -> u32 idx jt*8+lg*2+{0,1}.
#pragma unroll
        for (int jt = 0; jt < 4; ++jt){
            unsigned long long w =
                (unsigned long long)pack2bf(Pv[jt][0], Pv[jt][1]) |
                ((unsigned long long)pack2bf(Pv[jt][2], Pv[jt][3]) << 32);
            *reinterpret_cast<unsigned long long*>(&ptls[p][lq][jt*8 + lg*2]) = w;
        }
        // --- O^T += V^T·P^T : B-frag read back from LDS (b128, aligned) ---
#pragma unroll
        for (int kc = 0; kc < 2; ++kc){
            bf16x8 pfrag = *reinterpret_cast<const bf16x8*>(&ptls[p][lq][kc*16 + lg*4]);
#pragma unroll
            for (int ct = 0; ct < 4; ++ct){
                // A-operand: A[m = ct*16+lq (channel)][k = lg*8+j (key)] — contiguous 16B
                const __hip_bfloat16* vptr =
                    vp + (size_t)(b*C_CH + ct*16 + lq)*NPIX + (j0 + kc*32 + lg*8);
                bf16x8 vfrag = *reinterpret_cast<const bf16x8*>(vptr);
                Of[ct] = __builtin_amdgcn_mfma_f32_16x16x32_bf16(vfrag, pfrag, Of[ct], 0, 0, 0);
            }
        }
    }

    // --- stage partition partials in LDS ---
#pragma unroll
    for (int ct = 0; ct < 4; ++ct)
#pragma unroll
        for (int r = 0; r < 4; ++r) smem[p][(ct*4 + r)*64 + l] = Of[ct][r];
    if (l < 16){ smem[p][1024 + l] = m_run; smem[p][1040 + l] = l_run; }
    __syncthreads();

    // --- combine partitions + epilogue: out = x*(1+a2) + BN(gamma*O/L) ---
    {
        const int ct = threadIdx.x >> 6;   // each thread: 4 channels x 1 pixel
        float mp[KPART], lp[KPART];
#pragma unroll
        for (int q = 0; q < KPART; ++q){
            mp[q] = smem[q][1024 + lq];
            lp[q] = smem[q][1040 + lq];
        }
        float M = mp[0];
#pragma unroll
        for (int q = 1; q < KPART; ++q) M = fmaxf(M, mp[q]);
        float wgt[KPART], L = 0.f;
#pragma unroll
        for (int q = 0; q < KPART; ++q){
            wgt[q] = __expf(fminf(mp[q] - M, 0.f));
            L += lp[q] * wgt[q];
        }
        float invL = 1.f / L;
        float gam  = gamma[0];
        int n = qt*16 + lq;
#pragma unroll
        for (int r = 0; r < 4; ++r){
            float O = 0.f;
#pragma unroll
            for (int q = 0; q < KPART; ++q) O = fmaf(wgt[q], smem[q][(ct*4 + r)*64 + l], O);
            int c = ct*16 + lg*4 + r;
            float pam = gam * O * invL;
            pam = (pam - bnm[c]) * (bnw[c] * rsqrtf(bnv[c] + 1e-5f)) + bnb[c];
            float xv = x[(size_t)(b*C_CH + c)*NPIX + n];
            out[(size_t)(b*C_CH + c)*NPIX + n] = fmaf(xv, a2[b*C_CH + c], xv + pam);
        }
    }
}

extern "C" void kernel_launch(void* const* d_in, const int* in_sizes, int n_in,
                              void* d_out, int out_size, void* d_ws, size_t ws_size,
                              hipStream_t stream)
{
    const float* x     = (const float*)d_in[0];
    const float* wq    = (const float*)d_in[1];
    const float* bq    = (const float*)d_in[2];
    const float* wk    = (const float*)d_in[3];
    const float* bk    = (const float*)d_in[4];
    const float* wv    = (const float*)d_in[5];
    const float* bv    = (const float*)d_in[6];
    const float* gamma = (const float*)d_in[7];
    const float* bnw   = (const float*)d_in[8];
    const float* bnb   = (const float*)d_in[9];
    const float* bnm   = (const float*)d_in[10];
    const float* bnv   = (const float*)d_in[11];
    const float* sw1   = (const float*)d_in[12];
    const float* sb1   = (const float*)d_in[13];
    const float* s1w   = (const float*)d_in[14];
    const float* s1b   = (const float*)d_in[15];
    const float* s1m   = (const float*)d_in[16];
    const float* s1v   = (const float*)d_in[17];
    const float* sw2   = (const float*)d_in[18];
    const float* sb2   = (const float*)d_in[19];
    const float* s2w   = (const float*)d_in[20];
    const float* s2b   = (const float*)d_in[21];
    const float* s2m   = (const float*)d_in[22];
    const float* s2v   = (const float*)d_in[23];

    size_t off = 0;
    auto give = [&](size_t bytes) -> void* {
        void* r = (char*)d_ws + off;
        off += (bytes + 255) & ~(size_t)255;
        return r;
    };
    __hip_bfloat16* qp = (__hip_bfloat16*)give((size_t)B_SZ*NPIX*NQ*2);
    __hip_bfloat16* kp = (__hip_bfloat16*)give((size_t)B_SZ*NPIX*NQ*2);
    __hip_bfloat16* vp = (__hip_bfloat16*)give((size_t)B_SZ*C_CH*NPIX*2);
    float* amean = (float*)give((size_t)B_SZ*C_CH*4);
    float* a2    = (float*)give((size_t)B_SZ*C_CH*4);

    proj_qk<<<dim3(B_SZ*NPIX/256), dim3(256), 0, stream>>>(x, wq, bq, wk, bk, qp, kp);
    proj_v <<<dim3(B_SZ*4*NPIX/256), dim3(256), 0, stream>>>(x, wv, bv, vp);
    gap_kernel<<<dim3(B_SZ*C_CH), dim3(256), 0, stream>>>(x, amean);
    se_kernel<<<dim3(1), dim3(128), 0, stream>>>(amean, sw1, sb1, s1w, s1b, s1m, s1v,
                                                 sw2, sb2, s2w, s2b, s2m, s2v, a2);
    flash_fused<<<dim3(QTILES, B_SZ), dim3(256), 0, stream>>>(qp, kp, vp, a2, x, gamma,
                                                              bnw, bnb, bnm, bnv,
                                                              (float*)d_out);
}